// Round 5
// baseline (545.049 us; speedup 1.0000x reference)
//
#include <hip/hip_runtime.h>
#include <hip/hip_bf16.h>

#define NN   12288
#define EE   393216
#define BG   16
#define FIN  15
#define FH1  32
#define FH2  64
#define FEMB 64
#define NCL  11
#define BNEPS 1e-5f

static inline int cdiv(long a, long b){ return (int)((a + b - 1) / b); }

// ---- detect int64 vs int32 index buffers (x64-enabled reference emits int64) ----
__global__ void k_detect(const void* ei, const void* batch, int* flags){
  __shared__ int s0, s1;
  if (threadIdx.x == 0){ s0 = 1; s1 = 1; }
  __syncthreads();
  int k = threadIdx.x;           // 0..63
  const int* a = (const int*)ei;
  if (a[2*k + 1] != 0) atomicAnd(&s0, 0);
  const int* b = (const int*)batch;
  int j = 96*k;
  if (b[2*j + 1] != 0) atomicAnd(&s1, 0);
  __syncthreads();
  if (threadIdx.x == 0){ flags[0] = s0; flags[1] = s1; }
}

__device__ __forceinline__ int getIdx(const void* p, long i, int is64){
  return is64 ? (int)((const long long*)p)[i] : ((const int*)p)[i];
}

// ---- init: deg=1 (self loop) ----
__global__ void k_init(float* deg){
  int i = blockIdx.x*256 + threadIdx.x;
  if (i < NN) deg[i] = 1.0f;
}

__global__ void k_zero(float* p, int n){
  int i = blockIdx.x*256 + threadIdx.x;
  if (i < n) p[i] = 0.0f;
}

// ---- edge weights + degree scatter ----
__global__ void k_edge(const float* ea, const float* we, const float* bedg,
                       const void* ei, const int* flags, float* ew, float* deg){
  int e = blockIdx.x*256 + threadIdx.x;
  if (e >= EE) return;
  int is64 = flags[0];
  float z = ea[2*e]*we[0] + ea[2*e+1]*we[1] + bedg[0];
  float w = 1.0f/(1.0f + expf(-z));
  ew[e] = w;
  atomicAdd(&deg[getIdx(ei, e, is64)], w);
}

__global__ void k_dis(const float* deg, float* dis){
  int i = blockIdx.x*256 + threadIdx.x;
  if (i < NN) dis[i] = rsqrtf(deg[i]);   // deg >= 1 always (self loop weight 1)
}

// ---- sparse aggregation: Acc[row,f] += ew*dis[col]*Hin[col,f] ----
template<int F>
__global__ void k_scatter(const void* ei, const int* flags, const float* ew,
                          const float* dis, const float* Hin, float* Acc){
  int t = blockIdx.x*256 + threadIdx.x;
  int e = t / F;
  if (e >= EE) return;
  int is64 = flags[0];
  int f = t - e*F;
  int r = getIdx(ei, e, is64);
  int c = getIdx(ei, (long)EE + e, is64);
  atomicAdd(&Acc[r*F + f], ew[e]*dis[c]*Hin[c*F + f]);
}

// ---- add self loop + D^-1/2 scaling, in place ----
template<int F>
__global__ void k_scale(const float* dis, const float* Hin, float* Acc){
  int t = blockIdx.x*256 + threadIdx.x;
  if (t >= NN*F) return;
  int i = t / F;
  float d = dis[i];
  Acc[t] = d*(d*Hin[t] + Acc[t]);
}

// ---- Z = T @ W + b  (small dense) ----
template<int FI, int FO>
__global__ void k_gemm(const float* T, const float* W, const float* b, float* Z){
  int t = blockIdx.x*256 + threadIdx.x;
  if (t >= NN*FO) return;
  int i = t / FO, fo = t - i*FO;
  float s = b[fo];
  #pragma unroll
  for (int fi = 0; fi < FI; fi++) s += T[i*FI + fi]*W[fi*FO + fo];
  Z[t] = s;
}

// ---- per-column mean / rstd over N rows ----
__global__ void k_colreduce(const float* Z, float* mu, float* rinv, int FO){
  __shared__ float ss[256], sq[256];
  int fo = blockIdx.x;
  float s = 0.f, q = 0.f;
  for (int i = threadIdx.x; i < NN; i += 256){
    float z = Z[i*FO + fo]; s += z; q += z*z;
  }
  ss[threadIdx.x] = s; sq[threadIdx.x] = q;
  __syncthreads();
  for (int off = 128; off > 0; off >>= 1){
    if (threadIdx.x < off){ ss[threadIdx.x] += ss[threadIdx.x+off]; sq[threadIdx.x] += sq[threadIdx.x+off]; }
    __syncthreads();
  }
  if (threadIdx.x == 0){
    float mean = ss[0]/(float)NN;
    float var  = sq[0]/(float)NN - mean*mean;
    mu[fo] = mean; rinv[fo] = rsqrtf(var + BNEPS);
  }
}

// elementwise; safe with H == Z (in place)
template<int FO>
__global__ void k_bnrelu(const float* Z, const float* g, const float* be,
                         const float* mu, const float* rinv, float* H){
  int t = blockIdx.x*256 + threadIdx.x;
  if (t >= NN*FO) return;
  int fo = t % FO;
  float h = g[fo]*(Z[t] - mu[fo])*rinv[fo] + be[fo];
  H[t] = h > 0.f ? h : 0.f;
}

// ---- per-graph max pool (batch sorted; relu output >=0 so 0-init matches ref) ----
__global__ void k_pool(const float* H, const void* batch, const int* flags, float* embf){
  int is64 = flags[1];
  int b = blockIdx.x;
  int lo = 0, hi = NN;
  while (lo < hi){ int m = (lo+hi)>>1; if (getIdx(batch, m, is64) < b) lo = m+1; else hi = m; }
  int start = lo;
  lo = start; hi = NN;
  while (lo < hi){ int m = (lo+hi)>>1; if (getIdx(batch, m, is64) < b+1) lo = m+1; else hi = m; }
  int end = lo;
  int f = threadIdx.x & 63, grp = threadIdx.x >> 6;
  float m = 0.0f;
  for (int i = start + grp; i < end; i += 4) m = fmaxf(m, H[i*FEMB + f]);
  __shared__ float sh[4][64];
  sh[grp][f] = m;
  __syncthreads();
  if (grp == 0)
    embf[b*FEMB + f] = fmaxf(fmaxf(sh[0][f], sh[1][f]), fmaxf(sh[2][f], sh[3][f]));
}

// ---- whole MLP head in one block; output is FP32 (reference output dtype) ----
__global__ void __launch_bounds__(512) k_head(const float* embf,
    const float* wf1, const float* bf1, const float* gf1, const float* bef1,
    const float* wf2, const float* bf2, const float* gf2, const float* bef2,
    const float* wf3, const float* bf3, float* out){
  __shared__ float se[BG*64];
  __shared__ float s1[BG*512];
  __shared__ float s2[BG*256];
  __shared__ float sl[BG*NCL];
  int t = threadIdx.x;
  for (int i = t; i < BG*64; i += 512) se[i] = embf[i];
  __syncthreads();
  { // fc1: thread t owns column t of 512; BN over 16 rows is thread-local
    float z[BG];
    float bb = bf1[t];
    #pragma unroll
    for (int r = 0; r < BG; r++) z[r] = bb;
    for (int k = 0; k < 64; k++){
      float w = wf1[k*512 + t];
      #pragma unroll
      for (int r = 0; r < BG; r++) z[r] += se[r*64 + k]*w;
    }
    float s = 0.f, q = 0.f;
    #pragma unroll
    for (int r = 0; r < BG; r++){ s += z[r]; q += z[r]*z[r]; }
    float mean = s/(float)BG, var = q/(float)BG - (s/(float)BG)*(s/(float)BG);
    float inv = rsqrtf(var + BNEPS);
    float gg = gf1[t], bb2 = bef1[t];
    #pragma unroll
    for (int r = 0; r < BG; r++){
      float h = gg*(z[r] - mean)*inv + bb2;
      s1[r*512 + t] = h > 0.f ? h : 0.f;
    }
  }
  __syncthreads();
  if (t < 256){ // fc2
    float z[BG];
    float bb = bf2[t];
    #pragma unroll
    for (int r = 0; r < BG; r++) z[r] = bb;
    for (int k = 0; k < 512; k++){
      float w = wf2[k*256 + t];
      #pragma unroll
      for (int r = 0; r < BG; r++) z[r] += s1[r*512 + k]*w;
    }
    float s = 0.f, q = 0.f;
    #pragma unroll
    for (int r = 0; r < BG; r++){ s += z[r]; q += z[r]*z[r]; }
    float mean = s/(float)BG, var = q/(float)BG - (s/(float)BG)*(s/(float)BG);
    float inv = rsqrtf(var + BNEPS);
    float gg = gf2[t], bb2 = bef2[t];
    #pragma unroll
    for (int r = 0; r < BG; r++){
      float h = gg*(z[r] - mean)*inv + bb2;
      s2[r*256 + t] = h > 0.f ? h : 0.f;
    }
  }
  __syncthreads();
  if (t < BG*NCL){ // fc3
    int r = t / NCL, c = t - r*NCL;
    float s = bf3[c];
    for (int k = 0; k < 256; k++) s += s2[r*256 + k]*wf3[k*NCL + c];
    sl[t] = s;
  }
  __syncthreads();
  if (t < BG){ // log_softmax per row
    float m = -1e30f;
    for (int c = 0; c < NCL; c++) m = fmaxf(m, sl[t*NCL + c]);
    float s = 0.f;
    for (int c = 0; c < NCL; c++) s += expf(sl[t*NCL + c] - m);
    float lg = logf(s) + m;
    for (int c = 0; c < NCL; c++) out[t*NCL + c] = sl[t*NCL + c] - lg;
  }
  for (int i = t; i < BG*64; i += 512) out[BG*NCL + i] = se[i];
}

extern "C" void kernel_launch(void* const* d_in, const int* in_sizes, int n_in,
                              void* d_out, int out_size, void* d_ws, size_t ws_size,
                              hipStream_t stream){
  const float* x    = (const float*)d_in[0];
  const float* ea   = (const float*)d_in[1];
  const float* we   = (const float*)d_in[2];
  const float* bedg = (const float*)d_in[3];
  const float* w1   = (const float*)d_in[4];  const float* b1  = (const float*)d_in[5];
  const float* g1   = (const float*)d_in[6];  const float* be1 = (const float*)d_in[7];
  const float* w2   = (const float*)d_in[8];  const float* b2  = (const float*)d_in[9];
  const float* g2   = (const float*)d_in[10]; const float* be2 = (const float*)d_in[11];
  const float* w3   = (const float*)d_in[12]; const float* b3  = (const float*)d_in[13];
  const float* g3   = (const float*)d_in[14]; const float* be3 = (const float*)d_in[15];
  const float* wf1  = (const float*)d_in[16]; const float* bf1 = (const float*)d_in[17];
  const float* gf1  = (const float*)d_in[18]; const float* bef1= (const float*)d_in[19];
  const float* wf2  = (const float*)d_in[20]; const float* bf2 = (const float*)d_in[21];
  const float* gf2  = (const float*)d_in[22]; const float* bef2= (const float*)d_in[23];
  const float* wf3  = (const float*)d_in[24]; const float* bf3 = (const float*)d_in[25];
  const void* ei    = d_in[26];
  const void* batch = d_in[27];
  float* out = (float*)d_out;

  float* ws  = (float*)d_ws;
  float* ew   = ws; ws += EE;
  float* deg  = ws; ws += NN;
  float* dis  = ws; ws += NN;
  float* B0   = ws; ws += NN*64;   // Acc
  float* B1   = ws; ws += NN*64;
  float* B2   = ws; ws += NN*64;
  float* mu   = ws; ws += 64;
  float* rinv = ws; ws += 64;
  float* embf = ws; ws += BG*64;
  int*   flags= (int*)ws;

  k_detect<<<1, 64, 0, stream>>>(ei, batch, flags);
  k_init<<<cdiv(NN,256), 256, 0, stream>>>(deg);
  k_edge<<<cdiv(EE,256), 256, 0, stream>>>(ea, we, bedg, ei, flags, ew, deg);
  k_dis<<<cdiv(NN,256), 256, 0, stream>>>(deg, dis);

  // layer 1: x (15) -> B1 (32)
  k_zero<<<cdiv(NN*FIN,256), 256, 0, stream>>>(B0, NN*FIN);
  k_scatter<FIN><<<cdiv((long)EE*FIN,256), 256, 0, stream>>>(ei, flags, ew, dis, x, B0);
  k_scale<FIN><<<cdiv(NN*FIN,256), 256, 0, stream>>>(dis, x, B0);
  k_gemm<FIN,FH1><<<cdiv(NN*FH1,256), 256, 0, stream>>>(B0, w1, b1, B1);
  k_colreduce<<<FH1, 256, 0, stream>>>(B1, mu, rinv, FH1);
  k_bnrelu<FH1><<<cdiv(NN*FH1,256), 256, 0, stream>>>(B1, g1, be1, mu, rinv, B1);

  // layer 2: B1 (32) -> B2 (64)
  k_zero<<<cdiv(NN*FH1,256), 256, 0, stream>>>(B0, NN*FH1);
  k_scatter<FH1><<<cdiv((long)EE*FH1,256), 256, 0, stream>>>(ei, flags, ew, dis, B1, B0);
  k_scale<FH1><<<cdiv(NN*FH1,256), 256, 0, stream>>>(dis, B1, B0);
  k_gemm<FH1,FH2><<<cdiv(NN*FH2,256), 256, 0, stream>>>(B0, w2, b2, B2);
  k_colreduce<<<FH2, 256, 0, stream>>>(B2, mu, rinv, FH2);
  k_bnrelu<FH2><<<cdiv(NN*FH2,256), 256, 0, stream>>>(B2, g2, be2, mu, rinv, B2);

  // layer 3: B2 (64) -> B1 (64)
  k_zero<<<cdiv(NN*FH2,256), 256, 0, stream>>>(B0, NN*FH2);
  k_scatter<FH2><<<cdiv((long)EE*FH2,256), 256, 0, stream>>>(ei, flags, ew, dis, B2, B0);
  k_scale<FH2><<<cdiv(NN*FH2,256), 256, 0, stream>>>(dis, B2, B0);
  k_gemm<FH2,FEMB><<<cdiv(NN*FEMB,256), 256, 0, stream>>>(B0, w3, b3, B1);
  k_colreduce<<<FEMB, 256, 0, stream>>>(B1, mu, rinv, FEMB);
  k_bnrelu<FEMB><<<cdiv(NN*FEMB,256), 256, 0, stream>>>(B1, g3, be3, mu, rinv, B1);

  k_pool<<<BG, 256, 0, stream>>>(B1, batch, flags, embf);
  k_head<<<1, 512, 0, stream>>>(embf, wf1, bf1, gf1, bef1,
                                wf2, bf2, gf2, bef2, wf3, bf3, out);
}

// Round 6
// 533.624 us; speedup vs baseline: 1.0214x; 1.0214x over previous
//
#include <hip/hip_runtime.h>
#include <hip/hip_bf16.h>

#define NN   12288
#define EE   393216
#define BG   16
#define FIN  15
#define FH1  32
#define FH2  64
#define FEMB 64
#define NCL  11
#define BNEPS 1e-5f

static inline int cdiv(long a, long b){ return (int)((a + b - 1) / b); }

// ---- detect int64 vs int32 index buffers ----
__global__ void k_detect(const void* ei, const void* batch, int* flags){
  __shared__ int s0, s1;
  if (threadIdx.x == 0){ s0 = 1; s1 = 1; }
  __syncthreads();
  int k = threadIdx.x;           // 0..63
  const int* a = (const int*)ei;
  if (a[2*k + 1] != 0) atomicAnd(&s0, 0);
  const int* b = (const int*)batch;
  int j = 96*k;
  if (b[2*j + 1] != 0) atomicAnd(&s1, 0);
  __syncthreads();
  if (threadIdx.x == 0){ flags[0] = s0; flags[1] = s1; }
}

__device__ __forceinline__ int getIdx(const void* p, long i, int is64){
  return is64 ? (int)((const long long*)p)[i] : ((const int*)p)[i];
}

// ---- init: deg=1 (self loop), cnt=0, fill=0 ----
__global__ void k_init(float* deg, int* cnt, int* fill){
  int i = blockIdx.x*256 + threadIdx.x;
  if (i < NN){ deg[i] = 1.0f; cnt[i] = 0; fill[i] = 0; }
}

// ---- edge pass 1: degree (weighted) + row counts ----
__global__ void k_edge(const float* ea, const float* we, const float* bedg,
                       const void* ei, const int* flags, float* deg, int* cnt){
  int e = blockIdx.x*256 + threadIdx.x;
  if (e >= EE) return;
  int is64 = flags[0];
  float z = ea[2*e]*we[0] + ea[2*e+1]*we[1] + bedg[0];
  float w = 1.0f/(1.0f + expf(-z));
  int r = getIdx(ei, e, is64);
  atomicAdd(&deg[r], w);
  atomicAdd(&cnt[r], 1);
}

// ---- exclusive prefix sum over cnt (single block) ----
__global__ void k_scan(const int* cnt, int* rowptr){
  __shared__ int buf[256];
  __shared__ int carry;
  if (threadIdx.x == 0) carry = 0;
  __syncthreads();
  for (int base = 0; base < NN; base += 256){
    int v = cnt[base + threadIdx.x];
    buf[threadIdx.x] = v;
    __syncthreads();
    for (int off = 1; off < 256; off <<= 1){
      int add = (threadIdx.x >= off) ? buf[threadIdx.x - off] : 0;
      __syncthreads();
      buf[threadIdx.x] += add;
      __syncthreads();
    }
    rowptr[base + threadIdx.x] = carry + buf[threadIdx.x] - v;
    __syncthreads();
    if (threadIdx.x == 0) carry += buf[255];
    __syncthreads();
  }
}

__global__ void k_dis(const float* deg, float* dis){
  int i = blockIdx.x*256 + threadIdx.x;
  if (i < NN) dis[i] = rsqrtf(deg[i]);   // deg >= 1 (self loop weight 1)
}

// ---- edge pass 2: fill CSR (col + premultiplied weight ew*dis[col]) ----
__global__ void k_fill(const float* ea, const float* we, const float* bedg,
                       const void* ei, const int* flags, const float* dis,
                       const int* rowptr, int* fill, int* csr_col, float* csr_w){
  int e = blockIdx.x*256 + threadIdx.x;
  if (e >= EE) return;
  int is64 = flags[0];
  int r = getIdx(ei, e, is64);
  int c = getIdx(ei, (long)EE + e, is64);
  float z = ea[2*e]*we[0] + ea[2*e+1]*we[1] + bedg[0];
  float w = 1.0f/(1.0f + expf(-z));
  int slot = rowptr[r] + atomicAdd(&fill[r], 1);
  csr_col[slot] = c;
  csr_w[slot] = w * dis[c];
}

// ---- gather aggregation: Acc[i,f] = dis[i]*( dis[i]*H[i,f] + sum_e w'*H[c,f] )
// FP = padded feature width (threads per row); block 256; also zeros colstats.
template<int F, int FP>
__global__ void k_gather(const int* rowptr, const int* cnt, const int* csr_col,
                         const float* csr_w, const float* dis, const float* Hin,
                         float* Acc, float* colstats){
  if (blockIdx.x == 0 && threadIdx.x < 128) colstats[threadIdx.x] = 0.0f;
  int t = blockIdx.x*256 + threadIdx.x;
  int row = t / FP, f = t % FP;
  if (row >= NN || f >= F) return;
  float d = dis[row];
  float acc = d * Hin[row*F + f];          // self loop (weight 1) pre-scaled by dis[row]
  int beg = rowptr[row], n = cnt[row];
  for (int j = 0; j < n; j++){
    int c = csr_col[beg + j];
    float w = csr_w[beg + j];
    acc += w * Hin[c*F + f];
  }
  Acc[row*F + f] = d * acc;
}

// ---- Z = T @ W + b ----
template<int FI, int FO>
__global__ void k_gemm(const float* T, const float* W, const float* b, float* Z){
  int t = blockIdx.x*256 + threadIdx.x;
  if (t >= NN*FO) return;
  int i = t / FO, fo = t - i*FO;
  float s = b[fo];
  #pragma unroll
  for (int fi = 0; fi < FI; fi++) s += T[i*FI + fi]*W[fi*FO + fo];
  Z[t] = s;
}

// ---- per-column sum/sumsq (coalesced, F divides 256) ----
template<int F>
__global__ void k_colsum(const float* Z, float* colstats){
  __shared__ float ls[256], lq[256];
  float s = 0.f, q = 0.f;
  int stride = gridDim.x*256;
  for (int i = blockIdx.x*256 + threadIdx.x; i < NN*F; i += stride){
    float z = Z[i]; s += z; q += z*z;     // col = threadIdx.x % F (stride % F == 0)
  }
  ls[threadIdx.x] = s; lq[threadIdx.x] = q;
  __syncthreads();
  if (threadIdx.x < F){
    float as = 0.f, aq = 0.f;
    for (int j = threadIdx.x; j < 256; j += F){ as += ls[j]; aq += lq[j]; }
    atomicAdd(&colstats[threadIdx.x], as);
    atomicAdd(&colstats[64 + threadIdx.x], aq);
  }
}

// ---- BN (stats from colstats) + relu, in place ----
template<int FO>
__global__ void k_bnrelu(const float* Z, const float* g, const float* be,
                         const float* colstats, float* H){
  int t = blockIdx.x*256 + threadIdx.x;
  if (t >= NN*FO) return;
  int fo = t % FO;
  float mu  = colstats[fo] * (1.0f/(float)NN);
  float var = colstats[64+fo] * (1.0f/(float)NN) - mu*mu;
  float h = g[fo]*(Z[t] - mu)*rsqrtf(var + BNEPS) + be[fo];
  H[t] = h > 0.f ? h : 0.f;
}

// ---- per-graph max pool; also writes emb to out[BG*NCL ...] ----
__global__ void k_pool(const float* H, const void* batch, const int* flags,
                       float* embf, float* out){
  int is64 = flags[1];
  int b = blockIdx.x;
  int lo = 0, hi = NN;
  while (lo < hi){ int m = (lo+hi)>>1; if (getIdx(batch, m, is64) < b) lo = m+1; else hi = m; }
  int start = lo;
  lo = start; hi = NN;
  while (lo < hi){ int m = (lo+hi)>>1; if (getIdx(batch, m, is64) < b+1) lo = m+1; else hi = m; }
  int end = lo;
  int f = threadIdx.x & 63, grp = threadIdx.x >> 6;
  float m = 0.0f;
  for (int i = start + grp; i < end; i += 4) m = fmaxf(m, H[i*FEMB + f]);
  __shared__ float sh[4][64];
  sh[grp][f] = m;
  __syncthreads();
  if (grp == 0){
    float v = fmaxf(fmaxf(sh[0][f], sh[1][f]), fmaxf(sh[2][f], sh[3][f]));
    embf[b*FEMB + f] = v;
    out[BG*NCL + b*FEMB + f] = v;
  }
}

// ---- head fc1: 512 cols, thread = col; BN over 16 rows thread-local ----
__global__ void k_fc1(const float* embf, const float* wf1, const float* bf1,
                      const float* gf1, const float* bef1, float* s1g){
  int t = blockIdx.x*128 + threadIdx.x;   // 4 blocks x 128
  float z[BG];
  float bb = bf1[t];
  #pragma unroll
  for (int r = 0; r < BG; r++) z[r] = bb;
  for (int k = 0; k < 64; k++){
    float w = wf1[k*512 + t];
    #pragma unroll
    for (int r = 0; r < BG; r++) z[r] += embf[r*64 + k]*w;
  }
  float s = 0.f, q = 0.f;
  #pragma unroll
  for (int r = 0; r < BG; r++){ s += z[r]; q += z[r]*z[r]; }
  float mean = s/(float)BG, var = q/(float)BG - (s/(float)BG)*(s/(float)BG);
  float inv = rsqrtf(var + BNEPS);
  float gg = gf1[t], bb2 = bef1[t];
  #pragma unroll
  for (int r = 0; r < BG; r++){
    float h = gg*(z[r] - mean)*inv + bb2;
    s1g[r*512 + t] = h > 0.f ? h : 0.f;
  }
}

// ---- head fc2: 256 cols ----
__global__ void k_fc2(const float* s1g, const float* wf2, const float* bf2,
                      const float* gf2, const float* bef2, float* s2g){
  int t = blockIdx.x*64 + threadIdx.x;    // 4 blocks x 64
  float z[BG];
  float bb = bf2[t];
  #pragma unroll
  for (int r = 0; r < BG; r++) z[r] = bb;
  for (int k = 0; k < 512; k++){
    float w = wf2[k*256 + t];
    #pragma unroll
    for (int r = 0; r < BG; r++) z[r] += s1g[r*512 + k]*w;
  }
  float s = 0.f, q = 0.f;
  #pragma unroll
  for (int r = 0; r < BG; r++){ s += z[r]; q += z[r]*z[r]; }
  float mean = s/(float)BG, var = q/(float)BG - (s/(float)BG)*(s/(float)BG);
  float inv = rsqrtf(var + BNEPS);
  float gg = gf2[t], bb2 = bef2[t];
  #pragma unroll
  for (int r = 0; r < BG; r++){
    float h = gg*(z[r] - mean)*inv + bb2;
    s2g[r*256 + t] = h > 0.f ? h : 0.f;
  }
}

// ---- head fc3 + log_softmax ----
__global__ void k_fc3(const float* s2g, const float* wf3, const float* bf3, float* out){
  __shared__ float s2[BG*256];
  __shared__ float sl[BG*NCL];
  int t = threadIdx.x;
  for (int i = t; i < BG*256; i += 256) s2[i] = s2g[i];
  __syncthreads();
  if (t < BG*NCL){
    int r = t / NCL, c = t - r*NCL;
    float s = bf3[c];
    for (int k = 0; k < 256; k++) s += s2[r*256 + k]*wf3[k*NCL + c];
    sl[t] = s;
  }
  __syncthreads();
  if (t < BG){
    float m = -1e30f;
    for (int c = 0; c < NCL; c++) m = fmaxf(m, sl[t*NCL + c]);
    float s = 0.f;
    for (int c = 0; c < NCL; c++) s += expf(sl[t*NCL + c] - m);
    float lg = logf(s) + m;
    for (int c = 0; c < NCL; c++) out[t*NCL + c] = sl[t*NCL + c] - lg;
  }
}

extern "C" void kernel_launch(void* const* d_in, const int* in_sizes, int n_in,
                              void* d_out, int out_size, void* d_ws, size_t ws_size,
                              hipStream_t stream){
  const float* x    = (const float*)d_in[0];
  const float* ea   = (const float*)d_in[1];
  const float* we   = (const float*)d_in[2];
  const float* bedg = (const float*)d_in[3];
  const float* w1   = (const float*)d_in[4];  const float* b1  = (const float*)d_in[5];
  const float* g1   = (const float*)d_in[6];  const float* be1 = (const float*)d_in[7];
  const float* w2   = (const float*)d_in[8];  const float* b2  = (const float*)d_in[9];
  const float* g2   = (const float*)d_in[10]; const float* be2 = (const float*)d_in[11];
  const float* w3   = (const float*)d_in[12]; const float* b3  = (const float*)d_in[13];
  const float* g3   = (const float*)d_in[14]; const float* be3 = (const float*)d_in[15];
  const float* wf1  = (const float*)d_in[16]; const float* bf1 = (const float*)d_in[17];
  const float* gf1  = (const float*)d_in[18]; const float* bef1= (const float*)d_in[19];
  const float* wf2  = (const float*)d_in[20]; const float* bf2 = (const float*)d_in[21];
  const float* gf2  = (const float*)d_in[22]; const float* bef2= (const float*)d_in[23];
  const float* wf3  = (const float*)d_in[24]; const float* bf3 = (const float*)d_in[25];
  const void* ei    = d_in[26];
  const void* batch = d_in[27];
  float* out = (float*)d_out;

  float* ws  = (float*)d_ws;
  float* deg   = ws; ws += NN;
  float* dis   = ws; ws += NN;
  float* csr_w = ws; ws += EE;
  float* A     = ws; ws += NN*64;   // aggregation output
  float* P     = ws; ws += NN*64;   // layer activations / gemm output
  float* colstats = ws; ws += 128;  // [0:64] sum, [64:128] sumsq
  float* embf  = ws; ws += BG*64;
  float* s1g   = ws; ws += BG*512;
  float* s2g   = ws; ws += BG*256;
  int* cnt     = (int*)ws; ws += NN;
  int* fill    = (int*)ws; ws += NN;
  int* rowptr  = (int*)ws; ws += NN;
  int* csr_col = (int*)ws; ws += EE;
  int* flags   = (int*)ws;

  // graph preprocessing
  k_detect<<<1, 64, 0, stream>>>(ei, batch, flags);
  k_init<<<cdiv(NN,256), 256, 0, stream>>>(deg, cnt, fill);
  k_edge<<<cdiv(EE,256), 256, 0, stream>>>(ea, we, bedg, ei, flags, deg, cnt);
  k_scan<<<1, 256, 0, stream>>>(cnt, rowptr);
  k_dis<<<cdiv(NN,256), 256, 0, stream>>>(deg, dis);
  k_fill<<<cdiv(EE,256), 256, 0, stream>>>(ea, we, bedg, ei, flags, dis,
                                           rowptr, fill, csr_col, csr_w);

  // layer 1: x (15) -> P (32)
  k_gather<FIN,16><<<cdiv(NN*16,256), 256, 0, stream>>>(rowptr, cnt, csr_col, csr_w, dis, x, A, colstats);
  k_gemm<FIN,FH1><<<cdiv(NN*FH1,256), 256, 0, stream>>>(A, w1, b1, P);
  k_colsum<FH1><<<128, 256, 0, stream>>>(P, colstats);
  k_bnrelu<FH1><<<cdiv(NN*FH1,256), 256, 0, stream>>>(P, g1, be1, colstats, P);

  // layer 2: P (32) -> P (64)
  k_gather<FH1,32><<<cdiv(NN*32,256), 256, 0, stream>>>(rowptr, cnt, csr_col, csr_w, dis, P, A, colstats);
  k_gemm<FH1,FH2><<<cdiv(NN*FH2,256), 256, 0, stream>>>(A, w2, b2, P);
  k_colsum<FH2><<<128, 256, 0, stream>>>(P, colstats);
  k_bnrelu<FH2><<<cdiv(NN*FH2,256), 256, 0, stream>>>(P, g2, be2, colstats, P);

  // layer 3: P (64) -> P (64)
  k_gather<FH2,64><<<cdiv(NN*64,256), 256, 0, stream>>>(rowptr, cnt, csr_col, csr_w, dis, P, A, colstats);
  k_gemm<FH2,FEMB><<<cdiv(NN*FEMB,256), 256, 0, stream>>>(A, w3, b3, P);
  k_colsum<FEMB><<<128, 256, 0, stream>>>(P, colstats);
  k_bnrelu<FEMB><<<cdiv(NN*FEMB,256), 256, 0, stream>>>(P, g3, be3, colstats, P);

  // pool + head
  k_pool<<<BG, 256, 0, stream>>>(P, batch, flags, embf, out);
  k_fc1<<<4, 128, 0, stream>>>(embf, wf1, bf1, gf1, bef1, s1g);
  k_fc2<<<4, 64, 0, stream>>>(s1g, wf2, bf2, gf2, bef2, s2g);
  k_fc3<<<1, 256, 0, stream>>>(s2g, wf3, bf3, out);
}